// Round 8
// baseline (152.001 us; speedup 1.0000x reference)
//
#include <hip/hip_runtime.h>

// Problem constants (from reference): B=4, N=2048, IN_F=512, HEADS=8, D=64
#define BB   4
#define NN   2048
#define INF  512
#define HH   8
#define DD   64
#define BH   (BB*HH)   // 32
#define KSP  4         // k-split for V GEMM
#define NSUB 64        // 32-row subchunks per (b,h)

// ============================================================================
// A[b,h,i,j] = softmax_j( leaky_relu(q_j + k_i) ), H = A @ V.
// exp(leaky(x)) is piecewise multiplicative; sort j by q_j and the softmax
// collapses to prefix sums + a positional lookup. O(N·D).
// R8: merge-emit — sort thresholds (-k) too; emit outputs during the prefix
// sweep (two-pointer per 32-row subchunk). Deletes P1/P2 prefix arrays,
// k_off and k_out (21us -> ~7us). Harness fill floor ~92us is untouchable.
// ============================================================================

// -------- Kernel 1a: V partials. block = 64 rows x 64 cols x 128 k ----------
__global__ __launch_bounds__(256) void k_v(
    const float* __restrict__ X, const float* __restrict__ Wv,
    float* __restrict__ Vpart)   // [KSP][BB*NN][DD]
{
  __shared__ float Xs[64][68];
  __shared__ float Ws[64][68];
  const int t  = threadIdx.x;
  const int tr = t >> 4;
  const int tc = t & 15;
  const int rg = blockIdx.x >> 2;
  const int ks = blockIdx.x & 3;
  const int r0 = rg * 64;
  const int k0 = ks * 128;
  float acc[4][4] = {{0.f}};

  for (int kc = k0; kc < k0 + 128; kc += 64) {
    __syncthreads();
    #pragma unroll
    for (int i = 0; i < 4; i++) {
      const int e  = t + i * 256;
      const int rw = e >> 4;
      const int c4 = (e & 15) * 4;
      *(float4*)(&Xs[rw][c4]) = *(const float4*)(X  + (size_t)(r0 + rw) * INF + kc + c4);
      *(float4*)(&Ws[rw][c4]) = *(const float4*)(Wv + (size_t)(kc + rw) * DD  + c4);
    }
    __syncthreads();
    #pragma unroll 8
    for (int k = 0; k < 64; k++) {
      const float4 w4 = *(const float4*)(&Ws[k][tc * 4]);
      const float x0 = Xs[tr*4+0][k];
      const float x1 = Xs[tr*4+1][k];
      const float x2 = Xs[tr*4+2][k];
      const float x3 = Xs[tr*4+3][k];
      acc[0][0] += x0*w4.x; acc[0][1] += x0*w4.y; acc[0][2] += x0*w4.z; acc[0][3] += x0*w4.w;
      acc[1][0] += x1*w4.x; acc[1][1] += x1*w4.y; acc[1][2] += x1*w4.z; acc[1][3] += x1*w4.w;
      acc[2][0] += x2*w4.x; acc[2][1] += x2*w4.y; acc[2][2] += x2*w4.z; acc[2][3] += x2*w4.w;
      acc[3][0] += x3*w4.x; acc[3][1] += x3*w4.y; acc[3][2] += x3*w4.z; acc[3][3] += x3*w4.w;
    }
  }
  float* vp = Vpart + ((size_t)ks * (BB*NN) + r0) * DD;
  #pragma unroll
  for (int i = 0; i < 4; i++) {
    float4 o;  o.x = acc[i][0];  o.y = acc[i][1];  o.z = acc[i][2];  o.w = acc[i][3];
    *(float4*)(vp + (size_t)(4*tr + i) * DD + 4*tc) = o;
  }
}

// -------- Kernel 1b: V = sum(partials)+bv ; q,k scalar scores ---------------
__global__ __launch_bounds__(256) void k_vred(
    const float* __restrict__ Vpart, const float* __restrict__ bv,
    const float* __restrict__ Wq, const float* __restrict__ bq,
    const float* __restrict__ Wk, const float* __restrict__ bk,
    float* __restrict__ V, float* __restrict__ qsg, float* __restrict__ ksg)
{
  __shared__ float Vs[16][DD + 1];
  const int t  = threadIdx.x;
  const size_t e0 = ((size_t)blockIdx.x * 256 + t) * 4;
  const size_t STR = (size_t)BB * NN * DD;
  float4 a = *(const float4*)(Vpart + e0);
  #pragma unroll
  for (int p = 1; p < KSP; p++) {
    const float4 b = *(const float4*)(Vpart + (size_t)p * STR + e0);
    a.x += b.x;  a.y += b.y;  a.z += b.z;  a.w += b.w;
  }
  const float4 bb = *(const float4*)(bv + (e0 & 63));
  a.x += bb.x;  a.y += bb.y;  a.z += bb.z;  a.w += bb.w;
  *(float4*)(V + e0) = a;
  const int lrow = t >> 4;
  const int lcol = (t * 4) & 63;
  Vs[lrow][lcol]   = a.x;  Vs[lrow][lcol+1] = a.y;
  Vs[lrow][lcol+2] = a.z;  Vs[lrow][lcol+3] = a.w;
  __syncthreads();
  const int row = t >> 4;
  const int h   = t & 7;
  const bool isK = (t & 8) != 0;
  const float* W = isK ? Wk : Wq;
  float s = isK ? bk[h] : bq[h];
  #pragma unroll 8
  for (int dd = 0; dd < DD; dd++) s += Vs[row][dd] * W[dd*HH + h];
  const int grow = blockIdx.x * 16 + row;
  const int b = grow >> 11, n = grow & (NN - 1);
  (isK ? ksg : qsg)[(b*HH + h) * NN + n] = s;
}

// ------- Kernel 2: bitonic sort; blocks 0..31 sort q, 32..63 sort -k --------
__global__ __launch_bounds__(1024) void k_sort(
    float* __restrict__ qsg, const float* __restrict__ ksg,
    unsigned short* __restrict__ idxg,
    float* __restrict__ skt, unsigned short* __restrict__ idxk)
{
  __shared__ float key[NN];
  __shared__ int   idx[NN];
  const int t   = threadIdx.x;
  const bool isQ = blockIdx.x < BH;
  const int bh  = blockIdx.x & (BH - 1);
  {
    const int e0 = t, e1 = t + 1024;
    key[e0] = isQ ? qsg[bh*NN + e0] : -ksg[bh*NN + e0];   idx[e0] = e0;
    key[e1] = isQ ? qsg[bh*NN + e1] : -ksg[bh*NN + e1];   idx[e1] = e1;
  }
  __syncthreads();

#define CEX_STAGE(size, stride)                                         \
  {                                                                     \
    const int i = ((t & ~((stride) - 1)) << 1) | (t & ((stride) - 1));  \
    const int j = i + (stride);                                         \
    const bool up = ((i & (size)) == 0);                                \
    const float a = key[i], b = key[j];                                 \
    if (up ? (a > b) : (a < b)) {                                       \
      key[i] = b; key[j] = a;                                           \
      const int tmp = idx[i]; idx[i] = idx[j]; idx[j] = tmp;            \
    }                                                                   \
  }

  for (int size = 2; size <= 128; size <<= 1)
    for (int stride = size >> 1; stride > 0; stride >>= 1)
      CEX_STAGE(size, stride)          // wave-local, no barrier
  __syncthreads();
  for (int size = 256; size <= 2048; size <<= 1) {
    for (int stride = size >> 1; stride >= 128; stride >>= 1) {
      CEX_STAGE(size, stride)
      __syncthreads();
    }
    for (int stride = 64; stride > 0; stride >>= 1)
      CEX_STAGE(size, stride)          // wave-local
    __syncthreads();
  }
#undef CEX_STAGE

  if (isQ) {
    qsg[bh*NN + t]         = key[t];
    qsg[bh*NN + t + 1024]  = key[t + 1024];
    idxg[bh*NN + t]        = (unsigned short)idx[t];
    idxg[bh*NN + t + 1024] = (unsigned short)idx[t + 1024];
  } else {
    skt[bh*NN + t]         = key[t];
    skt[bh*NN + t + 1024]  = key[t + 1024];
    idxk[bh*NN + t]        = (unsigned short)idx[t];
    idxk[bh*NN + t + 1024] = (unsigned short)idx[t + 1024];
  }
}

// ------- Kernel 3: per-32-row subchunk sums (one pass, no barriers) ---------
__global__ __launch_bounds__(256) void k_csum(
    const float* __restrict__ sq, const unsigned short* __restrict__ idxg,
    const float* __restrict__ V,
    float* __restrict__ SubS1, float* __restrict__ SubS2,
    float* __restrict__ SubL1, float* __restrict__ SubL2)
{
  const int t  = threadIdx.x;
  const int d  = t & 63, w = t >> 6;
  const int bh = blockIdx.x >> 4;
  const int ck = blockIdx.x & 15;
  const int sub = ck*4 + w;
  const int rA = sub * 32;
  const float* Vb  = V + (size_t)(bh >> 3) * NN * DD;
  const float* sqb = sq + bh*NN;
  const unsigned short* ib = idxg + bh*NN;
  float a1 = 0.f, a2 = 0.f, s1 = 0.f, s2 = 0.f;
  #pragma unroll 8
  for (int rr = 0; rr < 32; ++rr) {
    const float qv = sqb[rA + rr];
    const float e1 = __expf(qv), e2 = __expf(0.01f*qv);
    const float v  = Vb[(size_t)ib[rA + rr]*DD + d];
    a1 += e1*v;  a2 += e2*v;  s1 += e1;  s2 += e2;
  }
  SubS1[((size_t)bh*NSUB + sub)*DD + d] = a1;
  SubS2[((size_t)bh*NSUB + sub)*DD + d] = a2;
  if (d == 0) { SubL1[bh*NSUB + sub] = s1;  SubL2[bh*NSUB + sub] = s2; }
}

// #{s[k] < x} over sorted s[0..NN): two-round 64-ary ballot search
__device__ __forceinline__ int lbound(const float* __restrict__ s, float x, int lane) {
  const unsigned long long m1 = __ballot(s[lane*32 + 31] < x);
  const int c1 = __popcll(m1);
  if (c1 == 64) return NN;
  const unsigned long long m2 = __ballot(s[c1*32 + (lane & 31)] < x);
  return c1*32 + (__popcll(m2) >> 1);
}

// ------- Kernel 4: merge-emit. wave = 32-row subchunk; no barriers ----------
__global__ __launch_bounds__(256) void k_merge(
    const float* __restrict__ sq, const unsigned short* __restrict__ idxg,
    const float* __restrict__ skt, const unsigned short* __restrict__ idxk,
    const float* __restrict__ V,
    const float* __restrict__ SubS1, const float* __restrict__ SubS2,
    const float* __restrict__ SubL1, const float* __restrict__ SubL2,
    float* __restrict__ out)
{
  __shared__ float vs[4*32*DD];              // 32 KB, wave-local slices
  __shared__ float e1s[4*32], e2s[4*32], qs[4*32];
  const int t   = threadIdx.x;
  const int d   = t & 63, w = t >> 6;
  const int bh  = blockIdx.x >> 4;
  const int ck  = blockIdx.x & 15;
  const int sub = ck*4 + w;
  const int rA  = sub * 32;
  const int b   = bh >> 3, h = bh & 7;
  const float* sqb  = sq  + bh*NN;
  const float* sktb = skt + bh*NN;
  const unsigned short* ib  = idxg + bh*NN;
  const unsigned short* ikb = idxk + bh*NN;
  const float* Vb = V + (size_t)b * NN * DD;

  // offsets: prefix of subchunk sums over [0, sub) + grand totals (L2-hot)
  float a1 = 0.f, a2 = 0.f, s1 = 0.f, s2 = 0.f, T1 = 0.f, Lt1 = 0.f;
  for (int s = 0; s < NSUB; ++s) {
    const float u1 = SubS1[((size_t)bh*NSUB + s)*DD + d];
    const float u2 = SubS2[((size_t)bh*NSUB + s)*DD + d];
    const float g1 = SubL1[bh*NSUB + s];
    const float g2 = SubL2[bh*NSUB + s];
    if (s < sub) { a1 += u1;  a2 += u2;  s1 += g1;  s2 += g2; }
    T1 += u1;  Lt1 += g1;
  }

  // stage exp/q scalars + 32 V rows into wave-local LDS (same-wave, in-order)
  if (d < 32) {
    const float qv = sqb[rA + d];
    qs [w*32 + d] = qv;
    e1s[w*32 + d] = __expf(qv);
    e2s[w*32 + d] = __expf(0.01f*qv);
  }
  #pragma unroll
  for (int rr = 0; rr < 32; ++rr)
    vs[(w*32 + rr)*DD + d] = Vb[(size_t)ib[rA + rr]*DD + d];

  // this wave's threshold range [jA, jB): pos in [rA, rA+32) (+NN for last)
  const int jA = (sub == 0)        ? 0  : lbound(sktb, sqb[rA - 1],  d);
  const int jB = (sub == NSUB - 1) ? NN : lbound(sktb, sqb[rA + 31], d);

  // two-pointer sweep: advance prefix past rows with q <= t_j, then emit
  int j = jA, r = 0;
  while (j < jB) {
    const float tj = sktb[j];
    while (r < 32 && qs[w*32 + r] <= tj) {
      const float e1 = e1s[w*32 + r], e2 = e2s[w*32 + r];
      const float vv = vs[(w*32 + r)*DD + d];
      a1 += e1*vv;  a2 += e2*vv;  s1 += e1;  s2 += e2;
      ++r;
    }
    const float kv  = -tj;
    const float ek  = __expf(kv);
    const float ek2 = __expf(0.01f*kv);
    const float num = ek*(T1 - a1)  + ek2*a2;
    const float den = ek*(Lt1 - s1) + ek2*s2;
    const int   i0  = ikb[j];
    out[((size_t)(b*NN + i0))*(HH*DD) + h*DD + d] = num / den;
    ++j;
  }
}

extern "C" void kernel_launch(void* const* d_in, const int* in_sizes, int n_in,
                              void* d_out, int out_size, void* d_ws, size_t ws_size,
                              hipStream_t stream)
{
  (void)in_sizes; (void)n_in; (void)out_size; (void)ws_size;
  const float* X  = (const float*)d_in[0];
  const float* Wv = (const float*)d_in[1];
  const float* bv = (const float*)d_in[2];
  const float* Wq = (const float*)d_in[3];
  const float* bq = (const float*)d_in[4];
  const float* Wk = (const float*)d_in[5];
  const float* bk = (const float*)d_in[6];
  float* out = (float*)d_out;

  // workspace carve-up (~12.7 MB, well under budget)
  float* w = (float*)d_ws;
  float* V     = w;  w += (size_t)BB*NN*DD;       // 524288
  float* qsg   = w;  w += BH*NN;                  // sorted in place
  float* ksg   = w;  w += BH*NN;
  float* skt   = w;  w += BH*NN;                  // sorted -k
  unsigned short* idxg = (unsigned short*)w;  w += BH*NN/2;
  unsigned short* idxk = (unsigned short*)w;  w += BH*NN/2;
  float* SubS1 = w;  w += (size_t)BH*NSUB*DD;     // 131072
  float* SubS2 = w;  w += (size_t)BH*NSUB*DD;
  float* SubL1 = w;  w += BH*NSUB;
  float* SubL2 = w;  w += BH*NSUB;
  float* Vpart = w;  w += (size_t)KSP*BB*NN*DD;   // 2097152

  k_v    <<<512, 256, 0, stream>>>(X, Wv, Vpart);
  k_vred <<<512, 256, 0, stream>>>(Vpart, bv, Wq, bq, Wk, bk, V, qsg, ksg);
  k_sort <<<2*BH, 1024, 0, stream>>>(qsg, ksg, idxg, skt, idxk);
  k_csum <<<BH*16, 256, 0, stream>>>(qsg, idxg, V, SubS1, SubS2, SubL1, SubL2);
  k_merge<<<BH*16, 256, 0, stream>>>(qsg, idxg, skt, idxk, V,
                                     SubS1, SubS2, SubL1, SubL2, out);
}

// Round 9
// 145.772 us; speedup vs baseline: 1.0427x; 1.0427x over previous
//
#include <hip/hip_runtime.h>

// Problem constants (from reference): B=4, N=2048, IN_F=512, HEADS=8, D=64
#define BB   4
#define NN   2048
#define INF  512
#define HH   8
#define DD   64
#define BH   (BB*HH)   // 32
#define NCK  16        // 128-row chunks per (b,h)
#define CKS  128       // chunk size
#define KSP  8         // k-split for V GEMM

// ============================================================================
// A[b,h,i,j] = softmax_j( leaky_relu(q_j + k_i) ), H = A @ V.
// exp(leaky(x)) is piecewise multiplicative; sort j by q_j and the softmax
// collapses to prefix sums + binary search. O(N·D).
// R8 lesson: serial merge-emit regressed — revert to R7 parallel pipeline.
// R9: k_v 8x8 thread tile, W-only LDS (X via L1-broadcast global float4) —
// LDS pipe 12->2.6us/CU, VALU-bound; k_out 4 i/wave; k_scan V stash in LDS.
// Harness 0xAA ws-poison (~90us) is inside dur_us and untouchable.
// ============================================================================

// -------- Kernel 1a: V partials. block = 128 rows x 64 cols x 64 k ----------
__global__ __launch_bounds__(128) void k_v(
    const float* __restrict__ X, const float* __restrict__ Wv,
    float* __restrict__ Vpart)   // [KSP][BB*NN][DD]
{
  __shared__ float Ws[64][68];      // [k][n], padded — 17.4 KB, staged once
  const int t  = threadIdx.x;
  const int tc = t & 7;             // col octet -> cols 8tc..8tc+7
  const int tr = t >> 3;            // row octet -> rows 8tr..8tr+7
  const int rg = blockIdx.x >> 3;   // 0..63
  const int ks = blockIdx.x & 7;    // k slice
  const int r0 = rg * 128;
  const int k0 = ks * 64;

  // stage Wv slice: 64k x 64n, coalesced float4, conflict-free
  #pragma unroll
  for (int i = 0; i < 8; i++) {
    const int e4 = t + i * 128;        // 1024 float4
    const int k  = e4 >> 4;
    const int n4 = (e4 & 15) * 4;
    *(float4*)(&Ws[k][n4]) = *(const float4*)(Wv + (size_t)(k0 + k) * DD + n4);
  }
  __syncthreads();

  float acc[8][8] = {{0.f}};
  const float* xbase = X + (size_t)(r0 + tr * 8) * INF + k0;
  for (int kk = 0; kk < 64; kk += 4) {
    float4 xv[8];
    #pragma unroll
    for (int r = 0; r < 8; r++)        // global f4; 8 lanes share each addr
      xv[r] = *(const float4*)(xbase + (size_t)r * INF + kk);
    #pragma unroll
    for (int j = 0; j < 4; j++) {
      const float4 wa = *(const float4*)(&Ws[kk + j][tc * 8]);
      const float4 wb = *(const float4*)(&Ws[kk + j][tc * 8 + 4]);
      #pragma unroll
      for (int r = 0; r < 8; r++) {
        const float x = (j == 0) ? xv[r].x : (j == 1) ? xv[r].y : (j == 2) ? xv[r].z : xv[r].w;
        acc[r][0] += x * wa.x;  acc[r][1] += x * wa.y;
        acc[r][2] += x * wa.z;  acc[r][3] += x * wa.w;
        acc[r][4] += x * wb.x;  acc[r][5] += x * wb.y;
        acc[r][6] += x * wb.z;  acc[r][7] += x * wb.w;
      }
    }
  }
  float* vp = Vpart + ((size_t)ks * (BB*NN) + r0 + tr * 8) * DD + tc * 8;
  #pragma unroll
  for (int r = 0; r < 8; r++) {
    float4 oa, ob;
    oa.x = acc[r][0]; oa.y = acc[r][1]; oa.z = acc[r][2]; oa.w = acc[r][3];
    ob.x = acc[r][4]; ob.y = acc[r][5]; ob.z = acc[r][6]; ob.w = acc[r][7];
    *(float4*)(vp + (size_t)r * DD)     = oa;
    *(float4*)(vp + (size_t)r * DD + 4) = ob;
  }
}

// -------- Kernel 1b: V = sum(partials)+bv ; q,k scalar scores ---------------
__global__ __launch_bounds__(256) void k_vred(
    const float* __restrict__ Vpart, const float* __restrict__ bv,
    const float* __restrict__ Wq, const float* __restrict__ bq,
    const float* __restrict__ Wk, const float* __restrict__ bk,
    float* __restrict__ V, float* __restrict__ qsg, float* __restrict__ ksg)
{
  __shared__ float Vs[16][DD + 1];
  const int t  = threadIdx.x;
  const size_t e0 = ((size_t)blockIdx.x * 256 + t) * 4;
  const size_t STR = (size_t)BB * NN * DD;
  float4 a = *(const float4*)(Vpart + e0);
  #pragma unroll
  for (int p = 1; p < KSP; p++) {
    const float4 b = *(const float4*)(Vpart + (size_t)p * STR + e0);
    a.x += b.x;  a.y += b.y;  a.z += b.z;  a.w += b.w;
  }
  const float4 bb = *(const float4*)(bv + (e0 & 63));
  a.x += bb.x;  a.y += bb.y;  a.z += bb.z;  a.w += bb.w;
  *(float4*)(V + e0) = a;
  const int lrow = t >> 4;
  const int lcol = (t * 4) & 63;
  Vs[lrow][lcol]   = a.x;  Vs[lrow][lcol+1] = a.y;
  Vs[lrow][lcol+2] = a.z;  Vs[lrow][lcol+3] = a.w;
  __syncthreads();
  const int row = t >> 4;
  const int h   = t & 7;
  const bool isK = (t & 8) != 0;
  const float* W = isK ? Wk : Wq;
  float s = isK ? bk[h] : bq[h];
  #pragma unroll 8
  for (int dd = 0; dd < DD; dd++) s += Vs[row][dd] * W[dd*HH + h];
  const int grow = blockIdx.x * 16 + row;
  const int b = grow >> 11, n = grow & (NN - 1);
  (isK ? ksg : qsg)[(b*HH + h) * NN + n] = s;
}

// ---------------- Kernel 2: bitonic sort of q per (b,h), in-place ------------
__global__ __launch_bounds__(1024) void k_sort(
    float* __restrict__ q, unsigned short* __restrict__ idxg)
{
  __shared__ float key[NN];
  __shared__ int   idx[NN];
  const int t  = threadIdx.x;
  const int bh = blockIdx.x;
  key[t]        = q[bh*NN + t];        idx[t]        = t;
  key[t + 1024] = q[bh*NN + t + 1024]; idx[t + 1024] = t + 1024;
  __syncthreads();

#define CEX_STAGE(size, stride)                                         \
  {                                                                     \
    const int i = ((t & ~((stride) - 1)) << 1) | (t & ((stride) - 1));  \
    const int j = i + (stride);                                         \
    const bool up = ((i & (size)) == 0);                                \
    const float a = key[i], b = key[j];                                 \
    if (up ? (a > b) : (a < b)) {                                       \
      key[i] = b; key[j] = a;                                           \
      const int tmp = idx[i]; idx[i] = idx[j]; idx[j] = tmp;            \
    }                                                                   \
  }

  for (int size = 2; size <= 128; size <<= 1)
    for (int stride = size >> 1; stride > 0; stride >>= 1)
      CEX_STAGE(size, stride)          // stride<=64: wave-local, no barrier
  __syncthreads();
  for (int size = 256; size <= 2048; size <<= 1) {
    for (int stride = size >> 1; stride >= 128; stride >>= 1) {
      CEX_STAGE(size, stride)
      __syncthreads();
    }
    for (int stride = 64; stride > 0; stride >>= 1)
      CEX_STAGE(size, stride)          // wave-local
    __syncthreads();
  }
#undef CEX_STAGE

  q[bh*NN + t]        = key[t];
  q[bh*NN + t + 1024] = key[t + 1024];
  idxg[bh*NN + t]        = (unsigned short)idx[t];
  idxg[bh*NN + t + 1024] = (unsigned short)idx[t + 1024];
}

// -------- Kernel 3: hierarchical scan — chunk-local prefixes + chunk sums ----
// V rows gathered once into wave-local LDS stash; pass 2 reads LDS.
__global__ __launch_bounds__(256) void k_scan(
    const float* __restrict__ sq, const unsigned short* __restrict__ idxg,
    const float* __restrict__ V,
    float* __restrict__ P1, float* __restrict__ P2,
    float* __restrict__ l1, float* __restrict__ l2,
    float* __restrict__ S1g, float* __restrict__ S2g,
    float* __restrict__ SL1, float* __restrict__ SL2)
{
  __shared__ float vstash[4][32][DD];   // 32 KB, wave-local slices
  __shared__ float ss1[4][64], ss2[4][64], sl1[4], sl2[4];
  const int t  = threadIdx.x;
  const int bh = blockIdx.x >> 4;
  const int ck = blockIdx.x & 15;
  const int d  = t & 63, g = t >> 6;
  const int r0 = ck*CKS + g*32;
  const float* Vb  = V + (size_t)(bh >> 3) * NN * DD;
  const float* sqb = sq + bh*NN;
  const unsigned short* ib = idxg + bh*NN;
  float a1 = 0.f, a2 = 0.f, s1 = 0.f, s2 = 0.f;
  #pragma unroll 8
  for (int rr = 0; rr < 32; rr++) {
    const int r = r0 + rr;
    const float qv = sqb[r];
    const float e1 = __expf(qv), e2 = __expf(0.01f*qv);
    const float v  = Vb[(size_t)ib[r]*DD + d];
    vstash[g][rr][d] = v;               // same-wave, in-order
    a1 += e1*v;  a2 += e2*v;  s1 += e1;  s2 += e2;
  }
  ss1[g][d] = a1;  ss2[g][d] = a2;
  if (d == 0) { sl1[g] = s1;  sl2[g] = s2; }
  __syncthreads();
  float o1 = 0.f, o2 = 0.f, lo1 = 0.f, lo2 = 0.f;
  for (int gg = 0; gg < g; gg++) { o1 += ss1[gg][d]; o2 += ss2[gg][d]; lo1 += sl1[gg]; lo2 += sl2[gg]; }
  if (g == 0) {   // chunk totals -> scratch (lives in d_out, dead before k_out)
    S1g[(bh*NCK + ck)*64 + d] = ss1[0][d]+ss1[1][d]+ss1[2][d]+ss1[3][d];
    S2g[(bh*NCK + ck)*64 + d] = ss2[0][d]+ss2[1][d]+ss2[2][d]+ss2[3][d];
    if (d == 0) {
      SL1[bh*NCK + ck] = sl1[0]+sl1[1]+sl1[2]+sl1[3];
      SL2[bh*NCK + ck] = sl2[0]+sl2[1]+sl2[2]+sl2[3];
    }
  }
  // pass 2: exclusive chunk-local prefixes; V from LDS stash
  a1 = o1; a2 = o2; s1 = lo1; s2 = lo2;
  float* P1b = P1 + (size_t)bh*NN*DD;
  float* P2b = P2 + (size_t)bh*NN*DD;
  #pragma unroll 8
  for (int rr = 0; rr < 32; rr++) {
    const int r = r0 + rr;
    const float qv = sqb[r];
    const float e1 = __expf(qv), e2 = __expf(0.01f*qv);
    const float v  = vstash[g][rr][d];
    P1b[(size_t)r*DD + d] = a1;
    P2b[(size_t)r*DD + d] = a2;
    if (d == 0) { l1[bh*NN + r] = s1;  l2[bh*NN + r] = s2; }
    a1 += e1*v;  a2 += e2*v;  s1 += e1;  s2 += e2;
  }
}

// ---------- Kernel 4: fp64 scan of the 16 chunk sums -> chunk offsets --------
__global__ __launch_bounds__(256) void k_off(
    const float* __restrict__ S1g, const float* __restrict__ S2g,
    const float* __restrict__ SL1, const float* __restrict__ SL2,
    float* __restrict__ Off1, float* __restrict__ Off2,
    float* __restrict__ Loff1, float* __restrict__ Loff2)
{
  const int bh = blockIdx.x;
  const int t  = threadIdx.x;
  if (t < 128) {
    const int d = t & 63;
    const bool h2 = t >= 64;
    const float* S = h2 ? S2g : S1g;
    float* O = h2 ? Off2 : Off1;
    double a = 0.0;
    for (int ck = 0; ck < NCK; ck++) {
      O[((size_t)bh*(NCK+1) + ck)*64 + d] = (float)a;
      a += (double)S[((size_t)bh*NCK + ck)*64 + d];
    }
    O[((size_t)bh*(NCK+1) + NCK)*64 + d] = (float)a;
  } else if (t == 128 || t == 129) {
    const bool h2 = (t == 129);
    const float* S = h2 ? SL2 : SL1;
    float* O = h2 ? Loff2 : Loff1;
    double a = 0.0;
    for (int ck = 0; ck < NCK; ck++) { O[bh*(NCK+1) + ck] = (float)a; a += (double)S[bh*NCK + ck]; }
    O[bh*(NCK+1) + NCK] = (float)a;
  }
}

// ------- Kernel 5: 64-ary search + combine + write; 4 i's per wave ----------
__global__ __launch_bounds__(256) void k_out(
    const float* __restrict__ sq, const float* __restrict__ ksg,
    const float* __restrict__ P1, const float* __restrict__ P2,
    const float* __restrict__ Off1, const float* __restrict__ Off2,
    const float* __restrict__ l1, const float* __restrict__ l2,
    const float* __restrict__ Loff1, const float* __restrict__ Loff2,
    float* __restrict__ out)
{
  const int t   = threadIdx.x;
  const int bh  = blockIdx.x >> 7;                       // 32 bh x 128 blocks
  const int loc = blockIdx.x & 127;
  const int w   = t >> 6;
  const int d   = t & 63;                                // lane id
  const int i0  = loc*16 + w*4;                          // 4 i's per wave
  const int b   = bh >> 3, h = bh & 7;
  const float* s = sq + bh*NN;
  const float probe = s[d*32 + 31];                      // shared round-1 table
  const float T1  = Off1[((size_t)bh*(NCK+1) + NCK)*64 + d];
  const float Lt1 = Loff1[bh*(NCK+1) + NCK];
  const size_t base = (size_t)bh * NN * DD;

  float kv[4], tt[4];
  int pos[4];
  #pragma unroll
  for (int u = 0; u < 4; u++) { kv[u] = ksg[bh*NN + i0 + u];  tt[u] = -kv[u]; }
  #pragma unroll
  for (int u = 0; u < 4; u++) {
    const unsigned long long m1 = __ballot(probe <= tt[u]);
    const int c1 = __popcll(m1);
    if (c1 == 64) pos[u] = NN;
    else {
      const unsigned long long m2 = __ballot(s[c1*32 + (d & 31)] <= tt[u]);
      pos[u] = c1*32 + (__popcll(m2) >> 1);
    }
  }
  #pragma unroll
  for (int u = 0; u < 4; u++) {
    const float ek  = __expf(kv[u]);
    const float ek2 = __expf(0.01f * kv[u]);
    float p1v, p2v, q1v, q2v;
    if (pos[u] < NN) {   // wave-uniform
      const int ch = pos[u] >> 7;
      p1v = P1[base + (size_t)pos[u]*DD + d] + Off1[((size_t)bh*(NCK+1) + ch)*64 + d];
      p2v = P2[base + (size_t)pos[u]*DD + d] + Off2[((size_t)bh*(NCK+1) + ch)*64 + d];
      q1v = l1[bh*NN + pos[u]] + Loff1[bh*(NCK+1) + ch];
      q2v = l2[bh*NN + pos[u]] + Loff2[bh*(NCK+1) + ch];
    } else {
      p1v = T1;   p2v = Off2[((size_t)bh*(NCK+1) + NCK)*64 + d];
      q1v = Lt1;  q2v = Loff2[bh*(NCK+1) + NCK];
    }
    const float num = ek * (T1 - p1v)  + ek2 * p2v;
    const float den = ek * (Lt1 - q1v) + ek2 * q2v;
    out[((size_t)(b*NN + i0 + u)) * (HH*DD) + h*DD + d] = num / den;
  }
}

extern "C" void kernel_launch(void* const* d_in, const int* in_sizes, int n_in,
                              void* d_out, int out_size, void* d_ws, size_t ws_size,
                              hipStream_t stream)
{
  (void)in_sizes; (void)n_in; (void)out_size; (void)ws_size;
  const float* X  = (const float*)d_in[0];
  const float* Wv = (const float*)d_in[1];
  const float* bv = (const float*)d_in[2];
  const float* Wq = (const float*)d_in[3];
  const float* bq = (const float*)d_in[4];
  const float* Wk = (const float*)d_in[5];
  const float* bk = (const float*)d_in[6];
  float* out = (float*)d_out;

  // workspace carve-up (~37 MB, within proven budget)
  float* w = (float*)d_ws;
  float* V     = w;  w += (size_t)BB*NN*DD;        // 524288
  float* qsg   = w;  w += BH*NN;                   // sorted in-place -> sq
  float* ksg   = w;  w += BH*NN;
  float* l1    = w;  w += BH*NN;
  float* l2    = w;  w += BH*NN;
  unsigned short* idxg = (unsigned short*)w;  w += BH*NN/2;
  float* Off1  = w;  w += BH*(NCK+1)*DD;
  float* Off2  = w;  w += BH*(NCK+1)*DD;
  float* Loff1 = w;  w += BH*(NCK+1);
  float* Loff2 = w;  w += BH*(NCK+1);
  float* P1    = w;  w += (size_t)BH*NN*DD;        // 4.19M floats (16.8 MB)
  float* P2    = w;  w += (size_t)BH*NN*DD;

  // V partials alias P1 (dead until k_scan): KSP x 2MB = 16.8 MB = sizeof(P1)
  float* Vpart = P1;

  // chunk-sum scratch lives in d_out: dead before k_out fully overwrites it
  float* S1g = out;
  float* S2g = S1g + BH*NCK*DD;
  float* SL1 = S2g + BH*NCK*DD;
  float* SL2 = SL1 + BH*NCK;

  k_v    <<<512, 128, 0, stream>>>(X, Wv, Vpart);
  k_vred <<<512, 256, 0, stream>>>(Vpart, bv, Wq, bq, Wk, bk, V, qsg, ksg);
  k_sort <<<BH, 1024, 0, stream>>>(qsg, idxg);
  k_scan <<<BH*NCK, 256, 0, stream>>>(qsg, idxg, V, P1, P2, l1, l2, S1g, S2g, SL1, SL2);
  k_off  <<<BH, 256, 0, stream>>>(S1g, S2g, SL1, SL2, Off1, Off2, Loff1, Loff2);
  k_out  <<<BH*128, 256, 0, stream>>>(qsg, ksg, P1, P2, Off1, Off2, l1, l2, Loff1, Loff2, out);
}

// Round 10
// 138.256 us; speedup vs baseline: 1.0994x; 1.0544x over previous
//
#include <hip/hip_runtime.h>

// Problem constants (from reference): B=4, N=2048, IN_F=512, HEADS=8, D=64
#define BB   4
#define NN   2048
#define INF  512
#define HH   8
#define DD   64
#define BH   (BB*HH)   // 32
#define NCK  16        // 128-row chunks per (b,h)
#define CKS  128       // chunk size
#define KSP  2         // k-split for V GEMM

// ============================================================================
// A[b,h,i,j] = softmax_j( leaky_relu(q_j + k_i) ), H = A @ V.
// exp(leaky(x)) is piecewise multiplicative; sort j by q_j and the softmax
// collapses to prefix sums + binary search. O(N·D).
// R9 calibration: LDS pipe is per-CU shared (~85B/cyc) -> GEMM LDS bytes/flop
// sets the floor. R10: k_v at 0.5B/flop (W-only LDS, b128/k; X via global
// broadcast f4), KSP=2 so Vpart traffic 8.4MB; k_off folded into k_out's
// LDS preamble. Harness 0xAA ws-poison (~90us) is inside dur_us, untouchable.
// ============================================================================

// ---- Kernel 1a: V partials. block = 32 rows x 64 cols x 256 k (one half) ---
__global__ __launch_bounds__(256) void k_v(
    const float* __restrict__ X, const float* __restrict__ Wv,
    float* __restrict__ Vpart)   // [KSP][BB*NN][DD]
{
  __shared__ float Ws[64][68];      // [k][n] chunk, padded — 17.4 KB
  const int t  = threadIdx.x;
  const int tc = t & 15;            // col quad -> cols 4tc..4tc+3
  const int tr = t >> 4;            // row pair -> rows 2tr, 2tr+1
  const int rg = blockIdx.x >> 1;   // 0..255: 32-row group
  const int kh = blockIdx.x & 1;    // k half
  const int r0 = rg * 32;
  const int k0 = kh * 256;
  float acc[2][4] = {{0.f}};

  for (int kc = 0; kc < 256; kc += 64) {
    __syncthreads();
    #pragma unroll
    for (int i = 0; i < 4; i++) {    // stage 64k x 64n, coalesced f4
      const int e4 = t + i * 256;
      const int k  = e4 >> 4;
      const int n4 = (e4 & 15) * 4;
      *(float4*)(&Ws[k][n4]) = *(const float4*)(Wv + (size_t)(k0 + kc + k) * DD + n4);
    }
    __syncthreads();
    const float* xp0 = X + (size_t)(r0 + tr * 2) * INF + k0 + kc;
    const float* xp1 = xp0 + INF;
    #pragma unroll 8
    for (int kk = 0; kk < 64; kk += 4) {
      const float4 xa = *(const float4*)(xp0 + kk);   // 16 lanes/addr bcast
      const float4 xb = *(const float4*)(xp1 + kk);
      #pragma unroll
      for (int j = 0; j < 4; j++) {
        const float4 w4 = *(const float4*)(&Ws[kk + j][tc * 4]);
        const float xaj = (j == 0) ? xa.x : (j == 1) ? xa.y : (j == 2) ? xa.z : xa.w;
        const float xbj = (j == 0) ? xb.x : (j == 1) ? xb.y : (j == 2) ? xb.z : xb.w;
        acc[0][0] += xaj * w4.x;  acc[0][1] += xaj * w4.y;
        acc[0][2] += xaj * w4.z;  acc[0][3] += xaj * w4.w;
        acc[1][0] += xbj * w4.x;  acc[1][1] += xbj * w4.y;
        acc[1][2] += xbj * w4.z;  acc[1][3] += xbj * w4.w;
      }
    }
  }
  float* vp = Vpart + ((size_t)kh * (BB*NN) + r0 + tr * 2) * DD + tc * 4;
  #pragma unroll
  for (int r = 0; r < 2; r++) {
    float4 o;  o.x = acc[r][0];  o.y = acc[r][1];  o.z = acc[r][2];  o.w = acc[r][3];
    *(float4*)(vp + (size_t)r * DD) = o;
  }
}

// -------- Kernel 1b: V = sum(partials)+bv ; q,k scalar scores ---------------
__global__ __launch_bounds__(256) void k_vred(
    const float* __restrict__ Vpart, const float* __restrict__ bv,
    const float* __restrict__ Wq, const float* __restrict__ bq,
    const float* __restrict__ Wk, const float* __restrict__ bk,
    float* __restrict__ V, float* __restrict__ qsg, float* __restrict__ ksg)
{
  __shared__ float Vs[16][DD + 1];
  const int t  = threadIdx.x;
  const size_t e0 = ((size_t)blockIdx.x * 256 + t) * 4;
  const size_t STR = (size_t)BB * NN * DD;
  float4 a = *(const float4*)(Vpart + e0);
  #pragma unroll
  for (int p = 1; p < KSP; p++) {
    const float4 b = *(const float4*)(Vpart + (size_t)p * STR + e0);
    a.x += b.x;  a.y += b.y;  a.z += b.z;  a.w += b.w;
  }
  const float4 bb = *(const float4*)(bv + (e0 & 63));
  a.x += bb.x;  a.y += bb.y;  a.z += bb.z;  a.w += bb.w;
  *(float4*)(V + e0) = a;
  const int lrow = t >> 4;
  const int lcol = (t * 4) & 63;
  Vs[lrow][lcol]   = a.x;  Vs[lrow][lcol+1] = a.y;
  Vs[lrow][lcol+2] = a.z;  Vs[lrow][lcol+3] = a.w;
  __syncthreads();
  const int row = t >> 4;
  const int h   = t & 7;
  const bool isK = (t & 8) != 0;
  const float* W = isK ? Wk : Wq;
  float s = isK ? bk[h] : bq[h];
  #pragma unroll 8
  for (int dd = 0; dd < DD; dd++) s += Vs[row][dd] * W[dd*HH + h];
  const int grow = blockIdx.x * 16 + row;
  const int b = grow >> 11, n = grow & (NN - 1);
  (isK ? ksg : qsg)[(b*HH + h) * NN + n] = s;
}

// ---------------- Kernel 2: bitonic sort of q per (b,h), in-place ------------
__global__ __launch_bounds__(1024) void k_sort(
    float* __restrict__ q, unsigned short* __restrict__ idxg)
{
  __shared__ float key[NN];
  __shared__ int   idx[NN];
  const int t  = threadIdx.x;
  const int bh = blockIdx.x;
  key[t]        = q[bh*NN + t];        idx[t]        = t;
  key[t + 1024] = q[bh*NN + t + 1024]; idx[t + 1024] = t + 1024;
  __syncthreads();

#define CEX_STAGE(size, stride)                                         \
  {                                                                     \
    const int i = ((t & ~((stride) - 1)) << 1) | (t & ((stride) - 1));  \
    const int j = i + (stride);                                         \
    const bool up = ((i & (size)) == 0);                                \
    const float a = key[i], b = key[j];                                 \
    if (up ? (a > b) : (a < b)) {                                       \
      key[i] = b; key[j] = a;                                           \
      const int tmp = idx[i]; idx[i] = idx[j]; idx[j] = tmp;            \
    }                                                                   \
  }

  for (int size = 2; size <= 128; size <<= 1)
    for (int stride = size >> 1; stride > 0; stride >>= 1)
      CEX_STAGE(size, stride)          // stride<=64: wave-local, no barrier
  __syncthreads();
  for (int size = 256; size <= 2048; size <<= 1) {
    for (int stride = size >> 1; stride >= 128; stride >>= 1) {
      CEX_STAGE(size, stride)
      __syncthreads();
    }
    for (int stride = 64; stride > 0; stride >>= 1)
      CEX_STAGE(size, stride)          // wave-local
    __syncthreads();
  }
#undef CEX_STAGE

  q[bh*NN + t]        = key[t];
  q[bh*NN + t + 1024] = key[t + 1024];
  idxg[bh*NN + t]        = (unsigned short)idx[t];
  idxg[bh*NN + t + 1024] = (unsigned short)idx[t + 1024];
}

// -------- Kernel 3: hierarchical scan — chunk-local prefixes + chunk sums ----
__global__ __launch_bounds__(256) void k_scan(
    const float* __restrict__ sq, const unsigned short* __restrict__ idxg,
    const float* __restrict__ V,
    float* __restrict__ P1, float* __restrict__ P2,
    float* __restrict__ l1, float* __restrict__ l2,
    float* __restrict__ S1g, float* __restrict__ S2g,
    float* __restrict__ SL1, float* __restrict__ SL2)
{
  __shared__ float vstash[4][32][DD];   // 32 KB, wave-local slices
  __shared__ float ss1[4][64], ss2[4][64], sl1[4], sl2[4];
  const int t  = threadIdx.x;
  const int bh = blockIdx.x >> 4;
  const int ck = blockIdx.x & 15;
  const int d  = t & 63, g = t >> 6;
  const int r0 = ck*CKS + g*32;
  const float* Vb  = V + (size_t)(bh >> 3) * NN * DD;
  const float* sqb = sq + bh*NN;
  const unsigned short* ib = idxg + bh*NN;
  float a1 = 0.f, a2 = 0.f, s1 = 0.f, s2 = 0.f;
  #pragma unroll 8
  for (int rr = 0; rr < 32; rr++) {
    const int r = r0 + rr;
    const float qv = sqb[r];
    const float e1 = __expf(qv), e2 = __expf(0.01f*qv);
    const float v  = Vb[(size_t)ib[r]*DD + d];
    vstash[g][rr][d] = v;               // same-wave, in-order
    a1 += e1*v;  a2 += e2*v;  s1 += e1;  s2 += e2;
  }
  ss1[g][d] = a1;  ss2[g][d] = a2;
  if (d == 0) { sl1[g] = s1;  sl2[g] = s2; }
  __syncthreads();
  float o1 = 0.f, o2 = 0.f, lo1 = 0.f, lo2 = 0.f;
  for (int gg = 0; gg < g; gg++) { o1 += ss1[gg][d]; o2 += ss2[gg][d]; lo1 += sl1[gg]; lo2 += sl2[gg]; }
  if (g == 0) {   // chunk totals (now in d_ws — no d_out aliasing)
    S1g[(bh*NCK + ck)*64 + d] = ss1[0][d]+ss1[1][d]+ss1[2][d]+ss1[3][d];
    S2g[(bh*NCK + ck)*64 + d] = ss2[0][d]+ss2[1][d]+ss2[2][d]+ss2[3][d];
    if (d == 0) {
      SL1[bh*NCK + ck] = sl1[0]+sl1[1]+sl1[2]+sl1[3];
      SL2[bh*NCK + ck] = sl2[0]+sl2[1]+sl2[2]+sl2[3];
    }
  }
  // pass 2: exclusive chunk-local prefixes; V from LDS stash
  a1 = o1; a2 = o2; s1 = lo1; s2 = lo2;
  float* P1b = P1 + (size_t)bh*NN*DD;
  float* P2b = P2 + (size_t)bh*NN*DD;
  #pragma unroll 8
  for (int rr = 0; rr < 32; rr++) {
    const int r = r0 + rr;
    const float qv = sqb[r];
    const float e1 = __expf(qv), e2 = __expf(0.01f*qv);
    const float v  = vstash[g][rr][d];
    P1b[(size_t)r*DD + d] = a1;
    P2b[(size_t)r*DD + d] = a2;
    if (d == 0) { l1[bh*NN + r] = s1;  l2[bh*NN + r] = s2; }
    a1 += e1*v;  a2 += e2*v;  s1 += e1;  s2 += e2;
  }
}

// ------- Kernel 4: offsets-in-LDS preamble + 64-ary search + write ----------
__global__ __launch_bounds__(256) void k_out(
    const float* __restrict__ sq, const float* __restrict__ ksg,
    const float* __restrict__ P1, const float* __restrict__ P2,
    const float* __restrict__ S1g, const float* __restrict__ S2g,
    const float* __restrict__ SL1, const float* __restrict__ SL2,
    const float* __restrict__ l1, const float* __restrict__ l2,
    float* __restrict__ out)
{
  __shared__ float Of1[NCK + 1][64], Of2[NCK + 1][64];
  __shared__ float Lo1[NCK + 1], Lo2[NCK + 1];
  const int t   = threadIdx.x;
  const int bh  = blockIdx.x >> 7;                       // 32 bh x 128 blocks
  const int loc = blockIdx.x & 127;
  const int w   = t >> 6;
  const int d   = t & 63;                                // lane id
  const int i0  = loc*16 + w*4;                          // 4 i's per wave
  const int b   = bh >> 3, h = bh & 7;

  // preamble: exclusive prefix of the 16 chunk sums (L2-hot, redundant/block)
  if (t < 64) {
    float a = 0.f;
    for (int ck = 0; ck < NCK; ck++) {
      Of1[ck][t] = a;  a += S1g[(bh*NCK + ck)*64 + t];
    }
    Of1[NCK][t] = a;
  } else if (t < 128) {
    const int dd = t - 64;
    float a = 0.f;
    for (int ck = 0; ck < NCK; ck++) {
      Of2[ck][dd] = a;  a += S2g[(bh*NCK + ck)*64 + dd];
    }
    Of2[NCK][dd] = a;
  } else if (t == 128) {
    float a = 0.f;
    for (int ck = 0; ck < NCK; ck++) { Lo1[ck] = a;  a += SL1[bh*NCK + ck]; }
    Lo1[NCK] = a;
  } else if (t == 129) {
    float a = 0.f;
    for (int ck = 0; ck < NCK; ck++) { Lo2[ck] = a;  a += SL2[bh*NCK + ck]; }
    Lo2[NCK] = a;
  }
  __syncthreads();

  const float* s = sq + bh*NN;
  const float probe = s[d*32 + 31];                      // shared round-1 table
  const float T1  = Of1[NCK][d];
  const float Lt1 = Lo1[NCK];
  const size_t base = (size_t)bh * NN * DD;

  float kv[4], tt[4];
  int pos[4];
  #pragma unroll
  for (int u = 0; u < 4; u++) { kv[u] = ksg[bh*NN + i0 + u];  tt[u] = -kv[u]; }
  #pragma unroll
  for (int u = 0; u < 4; u++) {
    const unsigned long long m1 = __ballot(probe <= tt[u]);
    const int c1 = __popcll(m1);
    if (c1 == 64) pos[u] = NN;
    else {
      const unsigned long long m2 = __ballot(s[c1*32 + (d & 31)] <= tt[u]);
      pos[u] = c1*32 + (__popcll(m2) >> 1);
    }
  }
  #pragma unroll
  for (int u = 0; u < 4; u++) {
    const float ek  = __expf(kv[u]);
    const float ek2 = __expf(0.01f * kv[u]);
    float p1v, p2v, q1v, q2v;
    if (pos[u] < NN) {   // wave-uniform
      const int ch = pos[u] >> 7;
      p1v = P1[base + (size_t)pos[u]*DD + d] + Of1[ch][d];
      p2v = P2[base + (size_t)pos[u]*DD + d] + Of2[ch][d];
      q1v = l1[bh*NN + pos[u]] + Lo1[ch];
      q2v = l2[bh*NN + pos[u]] + Lo2[ch];
    } else {
      p1v = T1;   p2v = Of2[NCK][d];
      q1v = Lt1;  q2v = Lo2[NCK];
    }
    const float num = ek * (T1 - p1v)  + ek2 * p2v;
    const float den = ek * (Lt1 - q1v) + ek2 * q2v;
    out[((size_t)(b*NN + i0 + u)) * (HH*DD) + h*DD + d] = num / den;
  }
}

extern "C" void kernel_launch(void* const* d_in, const int* in_sizes, int n_in,
                              void* d_out, int out_size, void* d_ws, size_t ws_size,
                              hipStream_t stream)
{
  (void)in_sizes; (void)n_in; (void)out_size; (void)ws_size;
  const float* X  = (const float*)d_in[0];
  const float* Wv = (const float*)d_in[1];
  const float* bv = (const float*)d_in[2];
  const float* Wq = (const float*)d_in[3];
  const float* bq = (const float*)d_in[4];
  const float* Wk = (const float*)d_in[5];
  const float* bk = (const float*)d_in[6];
  float* out = (float*)d_out;

  // workspace carve-up (~37 MB, within proven budget)
  float* w = (float*)d_ws;
  float* V     = w;  w += (size_t)BB*NN*DD;        // 524288
  float* qsg   = w;  w += BH*NN;                   // sorted in-place -> sq
  float* ksg   = w;  w += BH*NN;
  float* l1    = w;  w += BH*NN;
  float* l2    = w;  w += BH*NN;
  unsigned short* idxg = (unsigned short*)w;  w += BH*NN/2;
  float* S1g   = w;  w += (size_t)BH*NCK*DD;       // 32768 (in ws, not d_out)
  float* S2g   = w;  w += (size_t)BH*NCK*DD;
  float* SL1   = w;  w += BH*NCK;
  float* SL2   = w;  w += BH*NCK;
  float* P1    = w;  w += (size_t)BH*NN*DD;        // 16.8 MB
  float* P2    = w;  w += (size_t)BH*NN*DD;

  // V partials alias P1 (dead until k_scan): KSP x 2.1MB = 4.2 MB < sizeof(P1)
  float* Vpart = P1;

  k_v    <<<512, 256, 0, stream>>>(X, Wv, Vpart);
  k_vred <<<512, 256, 0, stream>>>(Vpart, bv, Wq, bq, Wk, bk, V, qsg, ksg);
  k_sort <<<BH, 1024, 0, stream>>>(qsg, idxg);
  k_scan <<<BH*NCK, 256, 0, stream>>>(qsg, idxg, V, P1, P2, l1, l2, S1g, S2g, SL1, SL2);
  k_out  <<<BH*128, 256, 0, stream>>>(qsg, ksg, P1, P2, S1g, S2g, SL1, SL2, l1, l2, out);
}